// Round 1
// baseline (419.160 us; speedup 1.0000x reference)
//
#include <hip/hip_runtime.h>
#include <hip/hip_bf16.h>

// Problem constants (verified against in_sizes at launch):
//   N = 100000 nodes, D = 64 features, E = 1250000 edges.
// Inputs (setup_inputs order):
//   d_in[0] old_g      [N,D] f32
//   d_in[1] W          [D,D] f32
//   d_in[2] edge_weight[E,1] f32
//   d_in[3] history_db [N,D] f32
//   d_in[4] src        [E]   i32
//   d_in[5] dst        [E]   i32
// Output: concat(nodes_new [N,D], history_new [N,D]) f32, out_size = 2*N*D.

#define D_FEAT 64

// ---------------------------------------------------------------------------
// K1: h = old_g @ W.  One wave per row; W staged in LDS; row broadcast via
// __shfl with compile-time lane index (compiles to v_readlane -> SGPR FMA).
// ---------------------------------------------------------------------------
__global__ void gemm64_kernel(const float* __restrict__ g,
                              const float* __restrict__ W,
                              float* __restrict__ h, int N) {
    __shared__ float Wl[D_FEAT * D_FEAT];
    for (int i = threadIdx.x; i < D_FEAT * D_FEAT; i += blockDim.x)
        Wl[i] = W[i];
    __syncthreads();

    const int lane = threadIdx.x & 63;
    const int wid  = threadIdx.x >> 6;
    const int wpb  = blockDim.x >> 6;

    for (int r = blockIdx.x * wpb + wid; r < N; r += gridDim.x * wpb) {
        float v = g[r * D_FEAT + lane];
        float acc = 0.0f;
#pragma unroll
        for (int k = 0; k < D_FEAT; ++k) {
            float gk = __shfl(v, k, 64);                 // broadcast row element k
            acc = fmaf(gk, Wl[k * D_FEAT + lane], acc);
        }
        h[r * D_FEAT + lane] = acc;
    }
}

// ---------------------------------------------------------------------------
// K2: per-edge message + scatter-add.  One wave per edge, lane = feature col.
// msg = tanh(h[src] + old_g[dst] * w);  atomicAdd into agg[dst].
// ---------------------------------------------------------------------------
__device__ __forceinline__ float fast_tanh(float x) {
    float ax = fabsf(x);
    float e  = __expf(-2.0f * ax);        // v_exp_f32 path
    float r  = (1.0f - e) / (1.0f + e);   // tanh(|x|)
    return copysignf(r, x);
}

__global__ void edge_kernel(const float* __restrict__ h,
                            const float* __restrict__ g,
                            const float* __restrict__ ew,
                            const int* __restrict__ src,
                            const int* __restrict__ dst,
                            float* __restrict__ agg, int E) {
    const int lane = threadIdx.x & 63;
    const int wid  = threadIdx.x >> 6;
    const int wpb  = blockDim.x >> 6;

    for (int e = blockIdx.x * wpb + wid; e < E; e += gridDim.x * wpb) {
        const int   s = src[e];
        const int   t = dst[e];
        const float w = ew[e];
        float x = h[s * D_FEAT + lane] + g[t * D_FEAT + lane] * w;
        float m = fast_tanh(x);
        atomicAdd(&agg[t * D_FEAT + lane], m);
    }
}

// ---------------------------------------------------------------------------
// K3: history_new = history_db + agg  (streaming, float4)
// ---------------------------------------------------------------------------
__global__ void finish_kernel(const float* __restrict__ agg,
                              const float* __restrict__ hist,
                              float* __restrict__ out1, int n4) {
    int i = blockIdx.x * blockDim.x + threadIdx.x;
    const int stride = gridDim.x * blockDim.x;
    for (; i < n4; i += stride) {
        float4 a  = reinterpret_cast<const float4*>(agg)[i];
        float4 hh = reinterpret_cast<const float4*>(hist)[i];
        float4 o;
        o.x = a.x + hh.x;
        o.y = a.y + hh.y;
        o.z = a.z + hh.z;
        o.w = a.w + hh.w;
        reinterpret_cast<float4*>(out1)[i] = o;
    }
}

extern "C" void kernel_launch(void* const* d_in, const int* in_sizes, int n_in,
                              void* d_out, int out_size, void* d_ws, size_t ws_size,
                              hipStream_t stream) {
    const float* old_g   = (const float*)d_in[0];
    const float* W       = (const float*)d_in[1];
    const float* ew      = (const float*)d_in[2];
    const float* hist    = (const float*)d_in[3];
    const int*   src     = (const int*)d_in[4];
    const int*   dst     = (const int*)d_in[5];

    const int N = in_sizes[0] / D_FEAT;
    const int E = in_sizes[4];
    const int ND = N * D_FEAT;

    float* out_nodes = (float*)d_out;          // agg accumulates here
    float* out_hist  = (float*)d_out + ND;     // history_db + agg

    float* h = (float*)d_ws;                   // [N,D] scratch (25.6 MB)

    // Zero the accumulation target (harness poisons d_out; we must re-zero
    // every call for determinism).
    hipMemsetAsync(out_nodes, 0, (size_t)ND * sizeof(float), stream);

    // K1: h = old_g @ W
    {
        const int block = 256;
        const int wpb = block / 64;
        int grid = (N + wpb - 1) / wpb;
        gemm64_kernel<<<grid, block, 0, stream>>>(old_g, W, h, N);
    }

    // K2: edge messages + scatter-add
    {
        const int block = 256;
        const int grid = 2048;                 // 8192 waves, grid-stride
        edge_kernel<<<grid, block, 0, stream>>>(h, old_g, ew, src, dst,
                                                out_nodes, E);
    }

    // K3: history_new = history + agg
    {
        const int block = 256;
        const int n4 = ND / 4;
        int grid = (n4 + block - 1) / block;
        if (grid > 2048) grid = 2048;
        finish_kernel<<<grid, block, 0, stream>>>(out_nodes, hist, out_hist, n4);
    }
}

// Round 2
// 395.139 us; speedup vs baseline: 1.0608x; 1.0608x over previous
//
#include <hip/hip_runtime.h>
#include <hip/hip_bf16.h>

// N = 100000 nodes, D = 64 features, E = 1250000 edges.
// Inputs: old_g[N,D] f32, W[D,D] f32, edge_weight[E,1] f32,
//         history_db[N,D] f32, src[E] i32, dst[E] i32
// Output: concat(nodes_new[N,D], history_new[N,D]) f32.
//
// Strategy: build CSR-by-dst each call (counting sort: histogram -> scan ->
// bucket fill of {src, weight} pairs), then one wave per dst node accumulates
// tanh(h[src] + old_g[dst]*w) in registers and writes both outputs once.
// No float atomics anywhere.

#define D_FEAT 64
#define SCAN_BLK 256
#define SCAN_CHUNK 1024   // 4 elements per thread

// ---------------------------------------------------------------------------
// K1: h = old_g @ W.  One wave per row; W staged in LDS.
// ---------------------------------------------------------------------------
__global__ void gemm64_kernel(const float* __restrict__ g,
                              const float* __restrict__ W,
                              float* __restrict__ h, int N) {
    __shared__ float Wl[D_FEAT * D_FEAT];
    for (int i = threadIdx.x; i < D_FEAT * D_FEAT; i += blockDim.x)
        Wl[i] = W[i];
    __syncthreads();

    const int lane = threadIdx.x & 63;
    const int wid  = threadIdx.x >> 6;
    const int wpb  = blockDim.x >> 6;

    for (int r = blockIdx.x * wpb + wid; r < N; r += gridDim.x * wpb) {
        float v = g[r * D_FEAT + lane];
        float acc = 0.0f;
#pragma unroll
        for (int k = 0; k < D_FEAT; ++k) {
            float gk = __shfl(v, k, 64);
            acc = fmaf(gk, Wl[k * D_FEAT + lane], acc);
        }
        h[r * D_FEAT + lane] = acc;
    }
}

// ---------------------------------------------------------------------------
// CSR build
// ---------------------------------------------------------------------------
__global__ void hist_kernel(const int* __restrict__ dst, int* __restrict__ cnt,
                            int E) {
    int i = blockIdx.x * blockDim.x + threadIdx.x;
    const int stride = gridDim.x * blockDim.x;
    for (; i < E; i += stride) atomicAdd(&cnt[dst[i]], 1);
}

__global__ void block_sum_kernel(const int* __restrict__ cnt, int n,
                                 int* __restrict__ blockSums) {
    __shared__ int lds[SCAN_BLK];
    const int base = blockIdx.x * SCAN_CHUNK;
    const int t = threadIdx.x;
    int s = 0;
#pragma unroll
    for (int i = 0; i < 4; ++i) {
        int idx = base + t * 4 + i;
        s += (idx < n) ? cnt[idx] : 0;
    }
    lds[t] = s;
    __syncthreads();
    for (int off = SCAN_BLK / 2; off > 0; off >>= 1) {
        if (t < off) lds[t] += lds[t + off];
        __syncthreads();
    }
    if (t == 0) blockSums[blockIdx.x] = lds[0];
}

__global__ void top_scan_kernel(int* __restrict__ blockSums, int nb) {
    if (threadIdx.x == 0 && blockIdx.x == 0) {
        int acc = 0;
        for (int i = 0; i < nb; ++i) {
            int v = blockSums[i];
            blockSums[i] = acc;
            acc += v;
        }
    }
}

__global__ void scan_fill_kernel(const int* __restrict__ cnt, int n,
                                 const int* __restrict__ blockSums,
                                 int* __restrict__ offsets,
                                 int* __restrict__ cursor, int E) {
    __shared__ int lds[SCAN_BLK];
    const int base = blockIdx.x * SCAN_CHUNK;
    const int t = threadIdx.x;
    int v[4];
    int s = 0;
#pragma unroll
    for (int i = 0; i < 4; ++i) {
        int idx = base + t * 4 + i;
        v[i] = (idx < n) ? cnt[idx] : 0;
        s += v[i];
    }
    lds[t] = s;
    __syncthreads();
    // inclusive Hillis-Steele scan of per-thread sums
    for (int off = 1; off < SCAN_BLK; off <<= 1) {
        int x = (t >= off) ? lds[t - off] : 0;
        __syncthreads();
        lds[t] += x;
        __syncthreads();
    }
    int run = lds[t] - s + blockSums[blockIdx.x];  // exclusive prefix
#pragma unroll
    for (int i = 0; i < 4; ++i) {
        int idx = base + t * 4 + i;
        if (idx < n) {
            offsets[idx] = run;
            cursor[idx]  = run;
            run += v[i];
        }
    }
    if (blockIdx.x == 0 && t == 0) offsets[n] = E;
}

__global__ void fill_kernel(const int* __restrict__ src,
                            const int* __restrict__ dst,
                            const float* __restrict__ ew,
                            int* __restrict__ cursor,
                            int2* __restrict__ srcw, int E) {
    int e = blockIdx.x * blockDim.x + threadIdx.x;
    const int stride = gridDim.x * blockDim.x;
    for (; e < E; e += stride) {
        int d = dst[e];
        int pos = atomicAdd(&cursor[d], 1);
        srcw[pos] = make_int2(src[e], __float_as_int(ew[e]));
    }
}

// ---------------------------------------------------------------------------
// K2: one wave per dst node; register accumulation; fused history output.
// ---------------------------------------------------------------------------
__device__ __forceinline__ float fast_tanh(float x) {
    float ax = fabsf(x);
    float e  = __expf(-2.0f * ax);
    float r  = (1.0f - e) / (1.0f + e);
    return copysignf(r, x);
}

__global__ void node_kernel(const float* __restrict__ h,
                            const float* __restrict__ g,
                            const float* __restrict__ hist,
                            const int* __restrict__ offsets,
                            const int2* __restrict__ srcw,
                            float* __restrict__ out_nodes,
                            float* __restrict__ out_hist, int N) {
    const int lane = threadIdx.x & 63;
    const int wid  = threadIdx.x >> 6;
    const int wpb  = blockDim.x >> 6;

    for (int n = blockIdx.x * wpb + wid; n < N; n += gridDim.x * wpb) {
        const int beg = offsets[n];
        const int end = offsets[n + 1];
        const float gd = g[n * D_FEAT + lane];
        float acc = 0.0f;

        int e = beg;
        // 2-wide software pipeline: two independent row gathers in flight
        for (; e + 1 < end; e += 2) {
            int2 sw0 = srcw[e];
            int2 sw1 = srcw[e + 1];
            float x0 = h[sw0.x * D_FEAT + lane] + gd * __int_as_float(sw0.y);
            float x1 = h[sw1.x * D_FEAT + lane] + gd * __int_as_float(sw1.y);
            acc += fast_tanh(x0);
            acc += fast_tanh(x1);
        }
        if (e < end) {
            int2 sw = srcw[e];
            float x = h[sw.x * D_FEAT + lane] + gd * __int_as_float(sw.y);
            acc += fast_tanh(x);
        }

        out_nodes[n * D_FEAT + lane] = acc;
        out_hist[n * D_FEAT + lane]  = hist[n * D_FEAT + lane] + acc;
    }
}

extern "C" void kernel_launch(void* const* d_in, const int* in_sizes, int n_in,
                              void* d_out, int out_size, void* d_ws, size_t ws_size,
                              hipStream_t stream) {
    const float* old_g = (const float*)d_in[0];
    const float* W     = (const float*)d_in[1];
    const float* ew    = (const float*)d_in[2];
    const float* hist  = (const float*)d_in[3];
    const int*   src   = (const int*)d_in[4];
    const int*   dst   = (const int*)d_in[5];

    const int N  = in_sizes[0] / D_FEAT;
    const int E  = in_sizes[4];
    const int ND = N * D_FEAT;

    float* out_nodes = (float*)d_out;
    float* out_hist  = (float*)d_out + ND;

    // Workspace layout (all 4-byte units; srcw kept 8B-aligned)
    char* ws = (char*)d_ws;
    float* h        = (float*)ws;                      ws += (size_t)ND * 4;
    int*   cnt      = (int*)ws;                        ws += (size_t)N * 4;
    int*   offsets  = (int*)ws;                        ws += (size_t)(N + 2) * 4;
    int*   cursor   = (int*)ws;                        ws += (size_t)N * 4;
    int*   blockSums= (int*)ws;                        ws += 1024 * 4;
    // align to 8
    ws = (char*)(((uintptr_t)ws + 7) & ~(uintptr_t)7);
    int2*  srcw     = (int2*)ws;

    const int nb = (N + SCAN_CHUNK - 1) / SCAN_CHUNK;

    hipMemsetAsync(cnt, 0, (size_t)N * sizeof(int), stream);

    // K1: h = old_g @ W
    {
        const int block = 256, wpb = block / 64;
        int grid = (N + wpb - 1) / wpb;
        gemm64_kernel<<<grid, block, 0, stream>>>(old_g, W, h, N);
    }

    // CSR build
    hist_kernel<<<2048, 256, 0, stream>>>(dst, cnt, E);
    block_sum_kernel<<<nb, SCAN_BLK, 0, stream>>>(cnt, N, blockSums);
    top_scan_kernel<<<1, 64, 0, stream>>>(blockSums, nb);
    scan_fill_kernel<<<nb, SCAN_BLK, 0, stream>>>(cnt, N, blockSums, offsets,
                                                  cursor, E);
    fill_kernel<<<2048, 256, 0, stream>>>(src, dst, ew, cursor, srcw, E);

    // K2: per-node accumulation + fused history
    {
        const int block = 256, wpb = block / 64;
        int grid = (N + wpb - 1) / wpb;
        if (grid > 8192) grid = 8192;
        node_kernel<<<grid, block, 0, stream>>>(h, old_g, hist, offsets, srcw,
                                                out_nodes, out_hist, N);
    }
}

// Round 4
// 273.132 us; speedup vs baseline: 1.5346x; 1.4467x over previous
//
#include <hip/hip_runtime.h>
#include <hip/hip_bf16.h>

// N = 100000 nodes, D = 64 features, E = 1250000 edges.
// Inputs: old_g[N,D] f32, W[D,D] f32, edge_weight[E,1] f32,
//         history_db[N,D] f32, src[E] i32, dst[E] i32
// Output: concat(nodes_new[N,D], history_new[N,D]) f32.
//
// Pipeline: (1) LDS-tiled fp32 GEMM h = old_g @ W;
//           (2) CSR-by-dst build (histogram -> scan -> bucket fill);
//           (3) one wave per dst node: register accumulation of
//               tanh(h[src] + old_g[dst]*w), fused history output.
// No float atomics anywhere.

#define D_FEAT 64
#define SCAN_BLK 256
#define SCAN_CHUNK 1024   // 4 elements per thread

// ---------------------------------------------------------------------------
// K1: h = old_g @ W.  Block = 256 threads -> 128-row x 64-col tile.
// Per thread: 4 rows x 8 cols. Gl padded to 66 words/row: row-group stride
// 264 B -> banks {0,8,16,24}x2 -> 2-way aliasing (free). W b128 reads are
// 8 distinct addrs broadcast x8 lanes -> 2-way (free).
// ---------------------------------------------------------------------------
#define GR 128
#define GPAD 66

__global__ __launch_bounds__(256) void gemm64_tile_kernel(
    const float* __restrict__ g, const float* __restrict__ W,
    float* __restrict__ h, int N) {
    __shared__ float Wl[D_FEAT * D_FEAT];
    __shared__ float Gl[GR][GPAD];

    const int tid = threadIdx.x;

    // stage W (16 KB) as float4
    {
        const float4* w4 = reinterpret_cast<const float4*>(W);
        float4* wl4 = reinterpret_cast<float4*>(Wl);
        for (int i = tid; i < D_FEAT * D_FEAT / 4; i += 256) wl4[i] = w4[i];
    }

    const int row0  = blockIdx.x * GR;
    const int nrows = min(GR, N - row0);

    // stage g tile: 8 float4 per thread, coalesced; LDS rows 8B-aligned (pad 66)
    for (int i = tid; i < GR * 16; i += 256) {
        const int r  = i >> 4;
        const int c4 = i & 15;
        if (r < nrows) {
            float4 v = reinterpret_cast<const float4*>(
                           g + (size_t)(row0 + r) * D_FEAT)[c4];
            float* dp = &Gl[r][c4 * 4];
            reinterpret_cast<float2*>(dp)[0] = make_float2(v.x, v.y);
            reinterpret_cast<float2*>(dp)[1] = make_float2(v.z, v.w);
        }
    }
    __syncthreads();

    const int cg = tid & 7;    // 8 col-groups of 8
    const int rg = tid >> 3;   // 32 row-groups of 4
    const int c0 = cg * 8;
    const int r0 = rg * 4;

    float acc[4][8];
#pragma unroll
    for (int i = 0; i < 4; ++i)
#pragma unroll
        for (int j = 0; j < 8; ++j) acc[i][j] = 0.0f;

#pragma unroll 4
    for (int k = 0; k < D_FEAT; ++k) {
        const float4 wa = *reinterpret_cast<const float4*>(&Wl[k * D_FEAT + c0]);
        const float4 wb = *reinterpret_cast<const float4*>(&Wl[k * D_FEAT + c0 + 4]);
        float gv[4];
#pragma unroll
        for (int i = 0; i < 4; ++i) gv[i] = Gl[r0 + i][k];
#pragma unroll
        for (int i = 0; i < 4; ++i) {
            acc[i][0] = fmaf(gv[i], wa.x, acc[i][0]);
            acc[i][1] = fmaf(gv[i], wa.y, acc[i][1]);
            acc[i][2] = fmaf(gv[i], wa.z, acc[i][2]);
            acc[i][3] = fmaf(gv[i], wa.w, acc[i][3]);
            acc[i][4] = fmaf(gv[i], wb.x, acc[i][4]);
            acc[i][5] = fmaf(gv[i], wb.y, acc[i][5]);
            acc[i][6] = fmaf(gv[i], wb.z, acc[i][6]);
            acc[i][7] = fmaf(gv[i], wb.w, acc[i][7]);
        }
    }

#pragma unroll
    for (int i = 0; i < 4; ++i) {
        const int r = r0 + i;
        if (r < nrows) {
            float* hp = h + (size_t)(row0 + r) * D_FEAT + c0;
            reinterpret_cast<float4*>(hp)[0] =
                make_float4(acc[i][0], acc[i][1], acc[i][2], acc[i][3]);
            reinterpret_cast<float4*>(hp)[1] =
                make_float4(acc[i][4], acc[i][5], acc[i][6], acc[i][7]);
        }
    }
}

// ---------------------------------------------------------------------------
// CSR build
// ---------------------------------------------------------------------------
__global__ void hist_kernel(const int* __restrict__ dst, int* __restrict__ cnt,
                            int E) {
    int i = blockIdx.x * blockDim.x + threadIdx.x;
    const int stride = gridDim.x * blockDim.x;
    for (; i < E; i += stride) atomicAdd(&cnt[dst[i]], 1);
}

__global__ void block_sum_kernel(const int* __restrict__ cnt, int n,
                                 int* __restrict__ blockSums) {
    __shared__ int lds[SCAN_BLK];
    const int base = blockIdx.x * SCAN_CHUNK;
    const int t = threadIdx.x;
    int s = 0;
#pragma unroll
    for (int i = 0; i < 4; ++i) {
        int idx = base + t * 4 + i;
        s += (idx < n) ? cnt[idx] : 0;
    }
    lds[t] = s;
    __syncthreads();
    for (int off = SCAN_BLK / 2; off > 0; off >>= 1) {
        if (t < off) lds[t] += lds[t + off];
        __syncthreads();
    }
    if (t == 0) blockSums[blockIdx.x] = lds[0];
}

__global__ void top_scan_kernel(int* __restrict__ blockSums, int nb) {
    if (threadIdx.x == 0 && blockIdx.x == 0) {
        int acc = 0;
        for (int i = 0; i < nb; ++i) {
            int v = blockSums[i];
            blockSums[i] = acc;
            acc += v;
        }
    }
}

__global__ void scan_fill_kernel(const int* __restrict__ cnt, int n,
                                 const int* __restrict__ blockSums,
                                 int* __restrict__ offsets,
                                 int* __restrict__ cursor, int E) {
    __shared__ int lds[SCAN_BLK];
    const int base = blockIdx.x * SCAN_CHUNK;
    const int t = threadIdx.x;
    int v[4];
    int s = 0;
#pragma unroll
    for (int i = 0; i < 4; ++i) {
        int idx = base + t * 4 + i;
        v[i] = (idx < n) ? cnt[idx] : 0;
        s += v[i];
    }
    lds[t] = s;
    __syncthreads();
    for (int off = 1; off < SCAN_BLK; off <<= 1) {
        int x = (t >= off) ? lds[t - off] : 0;
        __syncthreads();
        lds[t] += x;
        __syncthreads();
    }
    int run = lds[t] - s + blockSums[blockIdx.x];  // exclusive prefix
#pragma unroll
    for (int i = 0; i < 4; ++i) {
        int idx = base + t * 4 + i;
        if (idx < n) {
            offsets[idx] = run;
            cursor[idx]  = run;
            run += v[i];
        }
    }
    if (blockIdx.x == 0 && t == 0) offsets[n] = E;
}

__global__ void fill_kernel(const int* __restrict__ src,
                            const int* __restrict__ dst,
                            const float* __restrict__ ew,
                            int* __restrict__ cursor,
                            int2* __restrict__ srcw, int E) {
    int e = blockIdx.x * blockDim.x + threadIdx.x;
    const int stride = gridDim.x * blockDim.x;
    for (; e < E; e += stride) {
        int d = dst[e];
        int pos = atomicAdd(&cursor[d], 1);
        srcw[pos] = make_int2(src[e], __float_as_int(ew[e]));
    }
}

// ---------------------------------------------------------------------------
// K2: one wave per dst node; register accumulation; fused history output.
// ---------------------------------------------------------------------------
__device__ __forceinline__ float fast_tanh(float x) {
    float ax = fabsf(x);
    float e  = __expf(-2.0f * ax);
    float r  = (1.0f - e) / (1.0f + e);
    return copysignf(r, x);
}

__global__ void node_kernel(const float* __restrict__ h,
                            const float* __restrict__ g,
                            const float* __restrict__ hist,
                            const int* __restrict__ offsets,
                            const int2* __restrict__ srcw,
                            float* __restrict__ out_nodes,
                            float* __restrict__ out_hist, int N) {
    const int lane = threadIdx.x & 63;
    const int wid  = threadIdx.x >> 6;
    const int wpb  = blockDim.x >> 6;

    for (int n = blockIdx.x * wpb + wid; n < N; n += gridDim.x * wpb) {
        const int beg = offsets[n];
        const int end = offsets[n + 1];
        const float gd = g[n * D_FEAT + lane];
        float acc = 0.0f;

        int e = beg;
        // 4-wide software pipeline: four independent row gathers in flight
        for (; e + 3 < end; e += 4) {
            int2 sw0 = srcw[e];
            int2 sw1 = srcw[e + 1];
            int2 sw2 = srcw[e + 2];
            int2 sw3 = srcw[e + 3];
            float x0 = h[sw0.x * D_FEAT + lane] + gd * __int_as_float(sw0.y);
            float x1 = h[sw1.x * D_FEAT + lane] + gd * __int_as_float(sw1.y);
            float x2 = h[sw2.x * D_FEAT + lane] + gd * __int_as_float(sw2.y);
            float x3 = h[sw3.x * D_FEAT + lane] + gd * __int_as_float(sw3.y);
            acc += fast_tanh(x0);
            acc += fast_tanh(x1);
            acc += fast_tanh(x2);
            acc += fast_tanh(x3);
        }
        for (; e < end; ++e) {
            int2 sw = srcw[e];
            float x = h[sw.x * D_FEAT + lane] + gd * __int_as_float(sw.y);
            acc += fast_tanh(x);
        }

        out_nodes[n * D_FEAT + lane] = acc;
        out_hist[n * D_FEAT + lane]  = hist[n * D_FEAT + lane] + acc;
    }
}

extern "C" void kernel_launch(void* const* d_in, const int* in_sizes, int n_in,
                              void* d_out, int out_size, void* d_ws, size_t ws_size,
                              hipStream_t stream) {
    const float* old_g = (const float*)d_in[0];
    const float* W     = (const float*)d_in[1];
    const float* ew    = (const float*)d_in[2];
    const float* hist  = (const float*)d_in[3];
    const int*   src   = (const int*)d_in[4];
    const int*   dst   = (const int*)d_in[5];

    const int N  = in_sizes[0] / D_FEAT;
    const int E  = in_sizes[4];
    const int ND = N * D_FEAT;

    float* out_nodes = (float*)d_out;
    float* out_hist  = (float*)d_out + ND;

    // Workspace layout
    char* ws = (char*)d_ws;
    float* h        = (float*)ws;                      ws += (size_t)ND * 4;
    int*   cnt      = (int*)ws;                        ws += (size_t)N * 4;
    int*   offsets  = (int*)ws;                        ws += (size_t)(N + 2) * 4;
    int*   cursor   = (int*)ws;                        ws += (size_t)N * 4;
    int*   blockSums= (int*)ws;                        ws += 1024 * 4;
    ws = (char*)(((uintptr_t)ws + 7) & ~(uintptr_t)7);
    int2*  srcw     = (int2*)ws;

    const int nb = (N + SCAN_CHUNK - 1) / SCAN_CHUNK;

    hipMemsetAsync(cnt, 0, (size_t)N * sizeof(int), stream);

    // K1: h = old_g @ W (LDS-tiled)
    {
        int grid = (N + GR - 1) / GR;
        gemm64_tile_kernel<<<grid, 256, 0, stream>>>(old_g, W, h, N);
    }

    // CSR build
    hist_kernel<<<2048, 256, 0, stream>>>(dst, cnt, E);
    block_sum_kernel<<<nb, SCAN_BLK, 0, stream>>>(cnt, N, blockSums);
    top_scan_kernel<<<1, 64, 0, stream>>>(blockSums, nb);
    scan_fill_kernel<<<nb, SCAN_BLK, 0, stream>>>(cnt, N, blockSums, offsets,
                                                  cursor, E);
    fill_kernel<<<2048, 256, 0, stream>>>(src, dst, ew, cursor, srcw, E);

    // K2: per-node accumulation + fused history
    {
        const int block = 256, wpb = block / 64;
        int grid = (N + wpb - 1) / wpb;
        if (grid > 8192) grid = 8192;
        node_kernel<<<grid, block, 0, stream>>>(h, old_g, hist, offsets, srcw,
                                                out_nodes, out_hist, N);
    }
}

// Round 6
// 234.213 us; speedup vs baseline: 1.7896x; 1.1662x over previous
//
#include <hip/hip_runtime.h>
#include <hip/hip_bf16.h>

// N = 100000 nodes, D = 64 features, E = 1250000 edges.
// Inputs: old_g[N,D] f32, W[D,D] f32, edge_weight[E,1] f32,
//         history_db[N,D] f32, src[E] i32, dst[E] i32
// Output: concat(nodes_new[N,D], history_new[N,D]) f32.
//
// Pipeline: (1) LDS-tiled fp32 GEMM h = old_g @ W;
//           (2) CSR-by-dst build, XCD-partitioned (histogram -> scan ->
//               bucket fill with write-combining per XCD L2);
//           (3) one wave per dst node: register accumulation of
//               tanh(h[src] + old_g[dst]*w), fused history output.
// No float atomics anywhere.

#define D_FEAT 64
#define SCAN_BLK 256
#define SCAN_CHUNK 1024   // 4 elements per thread
#define NPART 8           // = #XCDs; blockIdx%8 ~ XCD (round-robin dispatch)

// ---------------------------------------------------------------------------
// K1: h = old_g @ W.  Block = 256 threads -> 128-row x 64-col tile.
// ---------------------------------------------------------------------------
#define GR 128
#define GPAD 66

__global__ __launch_bounds__(256) void gemm64_tile_kernel(
    const float* __restrict__ g, const float* __restrict__ W,
    float* __restrict__ h, int N) {
    __shared__ float Wl[D_FEAT * D_FEAT];
    __shared__ float Gl[GR][GPAD];

    const int tid = threadIdx.x;

    {
        const float4* w4 = reinterpret_cast<const float4*>(W);
        float4* wl4 = reinterpret_cast<float4*>(Wl);
        for (int i = tid; i < D_FEAT * D_FEAT / 4; i += 256) wl4[i] = w4[i];
    }

    const int row0  = blockIdx.x * GR;
    const int nrows = min(GR, N - row0);

    for (int i = tid; i < GR * 16; i += 256) {
        const int r  = i >> 4;
        const int c4 = i & 15;
        if (r < nrows) {
            float4 v = reinterpret_cast<const float4*>(
                           g + (size_t)(row0 + r) * D_FEAT)[c4];
            float* dp = &Gl[r][c4 * 4];
            reinterpret_cast<float2*>(dp)[0] = make_float2(v.x, v.y);
            reinterpret_cast<float2*>(dp)[1] = make_float2(v.z, v.w);
        }
    }
    __syncthreads();

    const int cg = tid & 7;
    const int rg = tid >> 3;
    const int c0 = cg * 8;
    const int r0 = rg * 4;

    float acc[4][8];
#pragma unroll
    for (int i = 0; i < 4; ++i)
#pragma unroll
        for (int j = 0; j < 8; ++j) acc[i][j] = 0.0f;

#pragma unroll 4
    for (int k = 0; k < D_FEAT; ++k) {
        const float4 wa = *reinterpret_cast<const float4*>(&Wl[k * D_FEAT + c0]);
        const float4 wb = *reinterpret_cast<const float4*>(&Wl[k * D_FEAT + c0 + 4]);
        float gv[4];
#pragma unroll
        for (int i = 0; i < 4; ++i) gv[i] = Gl[r0 + i][k];
#pragma unroll
        for (int i = 0; i < 4; ++i) {
            acc[i][0] = fmaf(gv[i], wa.x, acc[i][0]);
            acc[i][1] = fmaf(gv[i], wa.y, acc[i][1]);
            acc[i][2] = fmaf(gv[i], wa.z, acc[i][2]);
            acc[i][3] = fmaf(gv[i], wa.w, acc[i][3]);
            acc[i][4] = fmaf(gv[i], wb.x, acc[i][4]);
            acc[i][5] = fmaf(gv[i], wb.y, acc[i][5]);
            acc[i][6] = fmaf(gv[i], wb.z, acc[i][6]);
            acc[i][7] = fmaf(gv[i], wb.w, acc[i][7]);
        }
    }

#pragma unroll
    for (int i = 0; i < 4; ++i) {
        const int r = r0 + i;
        if (r < nrows) {
            float* hp = h + (size_t)(row0 + r) * D_FEAT + c0;
            reinterpret_cast<float4*>(hp)[0] =
                make_float4(acc[i][0], acc[i][1], acc[i][2], acc[i][3]);
            reinterpret_cast<float4*>(hp)[1] =
                make_float4(acc[i][4], acc[i][5], acc[i][6], acc[i][7]);
        }
    }
}

// ---------------------------------------------------------------------------
// CSR build — XCD-partitioned by dst range.
// Blocks with blockIdx%NPART==k handle only dst in [k*npp,(k+1)*npp): all
// atomics/writes for a given node come from ONE XCD -> lines accumulate all
// their writes in that XCD's L2 before eviction (write combining).
// ---------------------------------------------------------------------------
__global__ void hist_kernel(const int* __restrict__ dst, int* __restrict__ cnt,
                            int E, int npp) {
    const int part = blockIdx.x & (NPART - 1);
    const int lo = part * npp;
    const int hi = lo + npp;
    const int bid = blockIdx.x >> 3;
    const int nb  = gridDim.x >> 3;
    const int E4 = E >> 2;
    const int4* dst4 = reinterpret_cast<const int4*>(dst);

    int i = bid * blockDim.x + threadIdx.x;
    const int stride = nb * blockDim.x;
    for (; i < E4; i += stride) {
        int4 d = dst4[i];
        if (d.x >= lo && d.x < hi) atomicAdd(&cnt[d.x], 1);
        if (d.y >= lo && d.y < hi) atomicAdd(&cnt[d.y], 1);
        if (d.z >= lo && d.z < hi) atomicAdd(&cnt[d.z], 1);
        if (d.w >= lo && d.w < hi) atomicAdd(&cnt[d.w], 1);
    }
    // tail
    for (int e = E4 * 4 + bid * blockDim.x + threadIdx.x; e < E;
         e += nb * blockDim.x) {
        int d = dst[e];
        if (d >= lo && d < hi) atomicAdd(&cnt[d], 1);
    }
}

__global__ void block_sum_kernel(const int* __restrict__ cnt, int n,
                                 int* __restrict__ blockSums) {
    __shared__ int lds[SCAN_BLK];
    const int base = blockIdx.x * SCAN_CHUNK;
    const int t = threadIdx.x;
    int s = 0;
#pragma unroll
    for (int i = 0; i < 4; ++i) {
        int idx = base + t * 4 + i;
        s += (idx < n) ? cnt[idx] : 0;
    }
    lds[t] = s;
    __syncthreads();
    for (int off = SCAN_BLK / 2; off > 0; off >>= 1) {
        if (t < off) lds[t] += lds[t + off];
        __syncthreads();
    }
    if (t == 0) blockSums[blockIdx.x] = lds[0];
}

__global__ void top_scan_kernel(int* __restrict__ blockSums, int nb) {
    if (threadIdx.x == 0 && blockIdx.x == 0) {
        int acc = 0;
        for (int i = 0; i < nb; ++i) {
            int v = blockSums[i];
            blockSums[i] = acc;
            acc += v;
        }
    }
}

__global__ void scan_fill_kernel(const int* __restrict__ cnt, int n,
                                 const int* __restrict__ blockSums,
                                 int* __restrict__ offsets,
                                 int* __restrict__ cursor, int E) {
    __shared__ int lds[SCAN_BLK];
    const int base = blockIdx.x * SCAN_CHUNK;
    const int t = threadIdx.x;
    int v[4];
    int s = 0;
#pragma unroll
    for (int i = 0; i < 4; ++i) {
        int idx = base + t * 4 + i;
        v[i] = (idx < n) ? cnt[idx] : 0;
        s += v[i];
    }
    lds[t] = s;
    __syncthreads();
    for (int off = 1; off < SCAN_BLK; off <<= 1) {
        int x = (t >= off) ? lds[t - off] : 0;
        __syncthreads();
        lds[t] += x;
        __syncthreads();
    }
    int run = lds[t] - s + blockSums[blockIdx.x];  // exclusive prefix
#pragma unroll
    for (int i = 0; i < 4; ++i) {
        int idx = base + t * 4 + i;
        if (idx < n) {
            offsets[idx] = run;
            cursor[idx]  = run;
            run += v[i];
        }
    }
    if (blockIdx.x == 0 && t == 0) offsets[n] = E;
}

__global__ void fill_kernel(const int* __restrict__ src,
                            const int* __restrict__ dst,
                            const float* __restrict__ ew,
                            int* __restrict__ cursor,
                            int2* __restrict__ srcw, int E, int npp) {
    const int part = blockIdx.x & (NPART - 1);
    const int lo = part * npp;
    const int hi = lo + npp;
    const int bid = blockIdx.x >> 3;
    const int nb  = gridDim.x >> 3;
    const int E4 = E >> 2;
    const int4* dst4 = reinterpret_cast<const int4*>(dst);

    int i = bid * blockDim.x + threadIdx.x;
    const int stride = nb * blockDim.x;
    for (; i < E4; i += stride) {
        int4 d = dst4[i];
        const int e = i * 4;
        if (d.x >= lo && d.x < hi) {
            int pos = atomicAdd(&cursor[d.x], 1);
            srcw[pos] = make_int2(src[e + 0], __float_as_int(ew[e + 0]));
        }
        if (d.y >= lo && d.y < hi) {
            int pos = atomicAdd(&cursor[d.y], 1);
            srcw[pos] = make_int2(src[e + 1], __float_as_int(ew[e + 1]));
        }
        if (d.z >= lo && d.z < hi) {
            int pos = atomicAdd(&cursor[d.z], 1);
            srcw[pos] = make_int2(src[e + 2], __float_as_int(ew[e + 2]));
        }
        if (d.w >= lo && d.w < hi) {
            int pos = atomicAdd(&cursor[d.w], 1);
            srcw[pos] = make_int2(src[e + 3], __float_as_int(ew[e + 3]));
        }
    }
    // tail
    for (int e = E4 * 4 + bid * blockDim.x + threadIdx.x; e < E;
         e += nb * blockDim.x) {
        int d = dst[e];
        if (d >= lo && d < hi) {
            int pos = atomicAdd(&cursor[d], 1);
            srcw[pos] = make_int2(src[e], __float_as_int(ew[e]));
        }
    }
}

// ---------------------------------------------------------------------------
// K2: one wave per dst node; register accumulation; fused history output.
// ---------------------------------------------------------------------------
__device__ __forceinline__ float fast_tanh(float x) {
    float ax = fabsf(x);
    float e  = __expf(-2.0f * ax);
    float r  = (1.0f - e) / (1.0f + e);
    return copysignf(r, x);
}

__global__ void node_kernel(const float* __restrict__ h,
                            const float* __restrict__ g,
                            const float* __restrict__ hist,
                            const int* __restrict__ offsets,
                            const int2* __restrict__ srcw,
                            float* __restrict__ out_nodes,
                            float* __restrict__ out_hist, int N) {
    const int lane = threadIdx.x & 63;
    const int wid  = threadIdx.x >> 6;
    const int wpb  = blockDim.x >> 6;

    for (int n = blockIdx.x * wpb + wid; n < N; n += gridDim.x * wpb) {
        const int beg = offsets[n];
        const int end = offsets[n + 1];
        const float gd = g[n * D_FEAT + lane];
        float acc = 0.0f;

        int e = beg;
        for (; e + 3 < end; e += 4) {
            int2 sw0 = srcw[e];
            int2 sw1 = srcw[e + 1];
            int2 sw2 = srcw[e + 2];
            int2 sw3 = srcw[e + 3];
            float x0 = h[sw0.x * D_FEAT + lane] + gd * __int_as_float(sw0.y);
            float x1 = h[sw1.x * D_FEAT + lane] + gd * __int_as_float(sw1.y);
            float x2 = h[sw2.x * D_FEAT + lane] + gd * __int_as_float(sw2.y);
            float x3 = h[sw3.x * D_FEAT + lane] + gd * __int_as_float(sw3.y);
            acc += fast_tanh(x0);
            acc += fast_tanh(x1);
            acc += fast_tanh(x2);
            acc += fast_tanh(x3);
        }
        for (; e < end; ++e) {
            int2 sw = srcw[e];
            float x = h[sw.x * D_FEAT + lane] + gd * __int_as_float(sw.y);
            acc += fast_tanh(x);
        }

        out_nodes[n * D_FEAT + lane] = acc;
        out_hist[n * D_FEAT + lane]  = hist[n * D_FEAT + lane] + acc;
    }
}

extern "C" void kernel_launch(void* const* d_in, const int* in_sizes, int n_in,
                              void* d_out, int out_size, void* d_ws, size_t ws_size,
                              hipStream_t stream) {
    const float* old_g = (const float*)d_in[0];
    const float* W     = (const float*)d_in[1];
    const float* ew    = (const float*)d_in[2];
    const float* hist  = (const float*)d_in[3];
    const int*   src   = (const int*)d_in[4];
    const int*   dst   = (const int*)d_in[5];

    const int N  = in_sizes[0] / D_FEAT;
    const int E  = in_sizes[4];
    const int ND = N * D_FEAT;
    const int npp = (N + NPART - 1) / NPART;

    float* out_nodes = (float*)d_out;
    float* out_hist  = (float*)d_out + ND;

    // Workspace layout
    char* ws = (char*)d_ws;
    float* h        = (float*)ws;                      ws += (size_t)ND * 4;
    int*   cnt      = (int*)ws;                        ws += (size_t)N * 4;
    int*   offsets  = (int*)ws;                        ws += (size_t)(N + 2) * 4;
    int*   cursor   = (int*)ws;                        ws += (size_t)N * 4;
    int*   blockSums= (int*)ws;                        ws += 1024 * 4;
    ws = (char*)(((uintptr_t)ws + 7) & ~(uintptr_t)7);
    int2*  srcw     = (int2*)ws;

    const int nb = (N + SCAN_CHUNK - 1) / SCAN_CHUNK;

    hipMemsetAsync(cnt, 0, (size_t)N * sizeof(int), stream);

    // K1: h = old_g @ W (LDS-tiled)
    {
        int grid = (N + GR - 1) / GR;
        gemm64_tile_kernel<<<grid, 256, 0, stream>>>(old_g, W, h, N);
    }

    // CSR build (XCD-partitioned hist + fill)
    hist_kernel<<<2048, 256, 0, stream>>>(dst, cnt, E, npp);
    block_sum_kernel<<<nb, SCAN_BLK, 0, stream>>>(cnt, N, blockSums);
    top_scan_kernel<<<1, 64, 0, stream>>>(blockSums, nb);
    scan_fill_kernel<<<nb, SCAN_BLK, 0, stream>>>(cnt, N, blockSums, offsets,
                                                  cursor, E);
    fill_kernel<<<2048, 256, 0, stream>>>(src, dst, ew, cursor, srcw, E, npp);

    // K2: per-node accumulation + fused history
    {
        const int block = 256, wpb = block / 64;
        int grid = (N + wpb - 1) / wpb;
        if (grid > 8192) grid = 8192;
        node_kernel<<<grid, block, 0, stream>>>(h, old_g, hist, offsets, srcw,
                                                out_nodes, out_hist, N);
    }
}

// Round 9
// 222.887 us; speedup vs baseline: 1.8806x; 1.0508x over previous
//
#include <hip/hip_runtime.h>
#include <hip/hip_bf16.h>
#include <hip/hip_fp16.h>

// N = 100000 nodes, D = 64 features, E = 1250000 edges.
// Inputs: old_g[N,D] f32, W[D,D] f32, edge_weight[E,1] f32,
//         history_db[N,D] f32, src[E] i32, dst[E] i32
// Output: concat(nodes_new[N,D], history_new[N,D]) f32.
//
// Pipeline: (1) LDS-tiled fp32 GEMM h = old_g @ W, h stored as fp16
//               (halves gather traffic; |h|~O(1) so fp16 err ~5e-4);
//           (2) CSR-by-dst build, XCD-partitioned (write combining in L2);
//           (3) one wave per dst node: register accumulation of
//               tanh(h[src] + old_g[dst]*w), fused history output.
// No float atomics anywhere.

#define D_FEAT 64
#define SCAN_BLK 256
#define SCAN_CHUNK 1024   // 4 elements per thread
#define NPART 8           // = #XCDs; blockIdx%8 ~ XCD (round-robin dispatch)

// ---------------------------------------------------------------------------
// K1: h = old_g @ W.  Block = 256 threads -> 128-row x 64-col tile.
// Epilogue converts to fp16 and stores 8 halves (16 B) per thread-row.
// ---------------------------------------------------------------------------
#define GR 128
#define GPAD 66

__global__ __launch_bounds__(256) void gemm64_tile_kernel(
    const float* __restrict__ g, const float* __restrict__ W,
    __half* __restrict__ h16, int N) {
    __shared__ float Wl[D_FEAT * D_FEAT];
    __shared__ float Gl[GR][GPAD];

    const int tid = threadIdx.x;

    {
        const float4* w4 = reinterpret_cast<const float4*>(W);
        float4* wl4 = reinterpret_cast<float4*>(Wl);
        for (int i = tid; i < D_FEAT * D_FEAT / 4; i += 256) wl4[i] = w4[i];
    }

    const int row0  = blockIdx.x * GR;
    const int nrows = min(GR, N - row0);

    for (int i = tid; i < GR * 16; i += 256) {
        const int r  = i >> 4;
        const int c4 = i & 15;
        if (r < nrows) {
            float4 v = reinterpret_cast<const float4*>(
                           g + (size_t)(row0 + r) * D_FEAT)[c4];
            float* dp = &Gl[r][c4 * 4];
            reinterpret_cast<float2*>(dp)[0] = make_float2(v.x, v.y);
            reinterpret_cast<float2*>(dp)[1] = make_float2(v.z, v.w);
        }
    }
    __syncthreads();

    const int cg = tid & 7;
    const int rg = tid >> 3;
    const int c0 = cg * 8;
    const int r0 = rg * 4;

    float acc[4][8];
#pragma unroll
    for (int i = 0; i < 4; ++i)
#pragma unroll
        for (int j = 0; j < 8; ++j) acc[i][j] = 0.0f;

#pragma unroll 4
    for (int k = 0; k < D_FEAT; ++k) {
        const float4 wa = *reinterpret_cast<const float4*>(&Wl[k * D_FEAT + c0]);
        const float4 wb = *reinterpret_cast<const float4*>(&Wl[k * D_FEAT + c0 + 4]);
        float gv[4];
#pragma unroll
        for (int i = 0; i < 4; ++i) gv[i] = Gl[r0 + i][k];
#pragma unroll
        for (int i = 0; i < 4; ++i) {
            acc[i][0] = fmaf(gv[i], wa.x, acc[i][0]);
            acc[i][1] = fmaf(gv[i], wa.y, acc[i][1]);
            acc[i][2] = fmaf(gv[i], wa.z, acc[i][2]);
            acc[i][3] = fmaf(gv[i], wa.w, acc[i][3]);
            acc[i][4] = fmaf(gv[i], wb.x, acc[i][4]);
            acc[i][5] = fmaf(gv[i], wb.y, acc[i][5]);
            acc[i][6] = fmaf(gv[i], wb.z, acc[i][6]);
            acc[i][7] = fmaf(gv[i], wb.w, acc[i][7]);
        }
    }

#pragma unroll
    for (int i = 0; i < 4; ++i) {
        const int r = r0 + i;
        if (r < nrows) {
            __half2 hb[4];
#pragma unroll
            for (int j = 0; j < 4; ++j)
                hb[j] = __floats2half2_rn(acc[i][2 * j], acc[i][2 * j + 1]);
            *reinterpret_cast<uint4*>(h16 + (size_t)(row0 + r) * D_FEAT + c0) =
                *reinterpret_cast<uint4*>(hb);
        }
    }
}

// ---------------------------------------------------------------------------
// CSR build — XCD-partitioned by dst range.
// ---------------------------------------------------------------------------
__global__ void hist_kernel(const int* __restrict__ dst, int* __restrict__ cnt,
                            int E, int npp) {
    const int part = blockIdx.x & (NPART - 1);
    const int lo = part * npp;
    const int hi = lo + npp;
    const int bid = blockIdx.x >> 3;
    const int nb  = gridDim.x >> 3;
    const int E4 = E >> 2;
    const int4* dst4 = reinterpret_cast<const int4*>(dst);

    int i = bid * blockDim.x + threadIdx.x;
    const int stride = nb * blockDim.x;
    for (; i < E4; i += stride) {
        int4 d = dst4[i];
        if (d.x >= lo && d.x < hi) atomicAdd(&cnt[d.x], 1);
        if (d.y >= lo && d.y < hi) atomicAdd(&cnt[d.y], 1);
        if (d.z >= lo && d.z < hi) atomicAdd(&cnt[d.z], 1);
        if (d.w >= lo && d.w < hi) atomicAdd(&cnt[d.w], 1);
    }
    for (int e = E4 * 4 + bid * blockDim.x + threadIdx.x; e < E;
         e += nb * blockDim.x) {
        int d = dst[e];
        if (d >= lo && d < hi) atomicAdd(&cnt[d], 1);
    }
}

__global__ void block_sum_kernel(const int* __restrict__ cnt, int n,
                                 int* __restrict__ blockSums) {
    __shared__ int lds[SCAN_BLK];
    const int base = blockIdx.x * SCAN_CHUNK;
    const int t = threadIdx.x;
    int s = 0;
#pragma unroll
    for (int i = 0; i < 4; ++i) {
        int idx = base + t * 4 + i;
        s += (idx < n) ? cnt[idx] : 0;
    }
    lds[t] = s;
    __syncthreads();
    for (int off = SCAN_BLK / 2; off > 0; off >>= 1) {
        if (t < off) lds[t] += lds[t + off];
        __syncthreads();
    }
    if (t == 0) blockSums[blockIdx.x] = lds[0];
}

__global__ void top_scan_kernel(int* __restrict__ blockSums, int nb) {
    if (threadIdx.x == 0 && blockIdx.x == 0) {
        int acc = 0;
        for (int i = 0; i < nb; ++i) {
            int v = blockSums[i];
            blockSums[i] = acc;
            acc += v;
        }
    }
}

__global__ void scan_fill_kernel(const int* __restrict__ cnt, int n,
                                 const int* __restrict__ blockSums,
                                 int* __restrict__ offsets,
                                 int* __restrict__ cursor, int E) {
    __shared__ int lds[SCAN_BLK];
    const int base = blockIdx.x * SCAN_CHUNK;
    const int t = threadIdx.x;
    int v[4];
    int s = 0;
#pragma unroll
    for (int i = 0; i < 4; ++i) {
        int idx = base + t * 4 + i;
        v[i] = (idx < n) ? cnt[idx] : 0;
        s += v[i];
    }
    lds[t] = s;
    __syncthreads();
    for (int off = 1; off < SCAN_BLK; off <<= 1) {
        int x = (t >= off) ? lds[t - off] : 0;
        __syncthreads();
        lds[t] += x;
        __syncthreads();
    }
    int run = lds[t] - s + blockSums[blockIdx.x];  // exclusive prefix
#pragma unroll
    for (int i = 0; i < 4; ++i) {
        int idx = base + t * 4 + i;
        if (idx < n) {
            offsets[idx] = run;
            cursor[idx]  = run;
            run += v[i];
        }
    }
    if (blockIdx.x == 0 && t == 0) offsets[n] = E;
}

__global__ void fill_kernel(const int* __restrict__ src,
                            const int* __restrict__ dst,
                            const float* __restrict__ ew,
                            int* __restrict__ cursor,
                            int2* __restrict__ srcw, int E, int npp) {
    const int part = blockIdx.x & (NPART - 1);
    const int lo = part * npp;
    const int hi = lo + npp;
    const int bid = blockIdx.x >> 3;
    const int nb  = gridDim.x >> 3;
    const int E4 = E >> 2;
    const int4* dst4 = reinterpret_cast<const int4*>(dst);

    int i = bid * blockDim.x + threadIdx.x;
    const int stride = nb * blockDim.x;
    for (; i < E4; i += stride) {
        int4 d = dst4[i];
        const int e = i * 4;
        if (d.x >= lo && d.x < hi) {
            int pos = atomicAdd(&cursor[d.x], 1);
            srcw[pos] = make_int2(src[e + 0], __float_as_int(ew[e + 0]));
        }
        if (d.y >= lo && d.y < hi) {
            int pos = atomicAdd(&cursor[d.y], 1);
            srcw[pos] = make_int2(src[e + 1], __float_as_int(ew[e + 1]));
        }
        if (d.z >= lo && d.z < hi) {
            int pos = atomicAdd(&cursor[d.z], 1);
            srcw[pos] = make_int2(src[e + 2], __float_as_int(ew[e + 2]));
        }
        if (d.w >= lo && d.w < hi) {
            int pos = atomicAdd(&cursor[d.w], 1);
            srcw[pos] = make_int2(src[e + 3], __float_as_int(ew[e + 3]));
        }
    }
    for (int e = E4 * 4 + bid * blockDim.x + threadIdx.x; e < E;
         e += nb * blockDim.x) {
        int d = dst[e];
        if (d >= lo && d < hi) {
            int pos = atomicAdd(&cursor[d], 1);
            srcw[pos] = make_int2(src[e], __float_as_int(ew[e]));
        }
    }
}

// ---------------------------------------------------------------------------
// K2: one wave per dst node; register accumulation; fused history output.
// tanh via exp2 + raw v_rcp: ~8 VALU/edge.
// ---------------------------------------------------------------------------
__device__ __forceinline__ float fast_tanh(float x) {
    float ax = fabsf(x);
    float e  = __builtin_amdgcn_exp2f(-2.885390082f * ax);   // exp(-2|x|)
    float r  = __builtin_amdgcn_rcpf(1.0f + e);
    float t  = fmaf(-2.0f * e, r, 1.0f);                     // (1-e)/(1+e)
    return copysignf(t, x);
}

__global__ void node_kernel(const __half* __restrict__ h16,
                            const float* __restrict__ g,
                            const float* __restrict__ hist,
                            const int* __restrict__ offsets,
                            const int2* __restrict__ srcw,
                            float* __restrict__ out_nodes,
                            float* __restrict__ out_hist, int N) {
    const int lane = threadIdx.x & 63;
    const int wid  = threadIdx.x >> 6;
    const int wpb  = blockDim.x >> 6;

    for (int n = blockIdx.x * wpb + wid; n < N; n += gridDim.x * wpb) {
        const int beg = offsets[n];
        const int end = offsets[n + 1];
        const float gd = g[n * D_FEAT + lane];
        float acc = 0.0f;

        int e = beg;
        for (; e + 3 < end; e += 4) {
            int2 sw0 = srcw[e];
            int2 sw1 = srcw[e + 1];
            int2 sw2 = srcw[e + 2];
            int2 sw3 = srcw[e + 3];
            float h0 = __half2float(h16[(size_t)sw0.x * D_FEAT + lane]);
            float h1 = __half2float(h16[(size_t)sw1.x * D_FEAT + lane]);
            float h2 = __half2float(h16[(size_t)sw2.x * D_FEAT + lane]);
            float h3 = __half2float(h16[(size_t)sw3.x * D_FEAT + lane]);
            acc += fast_tanh(fmaf(gd, __int_as_float(sw0.y), h0));
            acc += fast_tanh(fmaf(gd, __int_as_float(sw1.y), h1));
            acc += fast_tanh(fmaf(gd, __int_as_float(sw2.y), h2));
            acc += fast_tanh(fmaf(gd, __int_as_float(sw3.y), h3));
        }
        for (; e < end; ++e) {
            int2 sw = srcw[e];
            float hv = __half2float(h16[(size_t)sw.x * D_FEAT + lane]);
            acc += fast_tanh(fmaf(gd, __int_as_float(sw.y), hv));
        }

        out_nodes[n * D_FEAT + lane] = acc;
        out_hist[n * D_FEAT + lane]  = hist[n * D_FEAT + lane] + acc;
    }
}

extern "C" void kernel_launch(void* const* d_in, const int* in_sizes, int n_in,
                              void* d_out, int out_size, void* d_ws, size_t ws_size,
                              hipStream_t stream) {
    const float* old_g = (const float*)d_in[0];
    const float* W     = (const float*)d_in[1];
    const float* ew    = (const float*)d_in[2];
    const float* hist  = (const float*)d_in[3];
    const int*   src   = (const int*)d_in[4];
    const int*   dst   = (const int*)d_in[5];

    const int N  = in_sizes[0] / D_FEAT;
    const int E  = in_sizes[4];
    const int ND = N * D_FEAT;
    const int npp = (N + NPART - 1) / NPART;

    float* out_nodes = (float*)d_out;
    float* out_hist  = (float*)d_out + ND;

    // Workspace layout (h region kept at ND*4 bytes for layout stability;
    // only ND*2 used now that h is fp16)
    char* ws = (char*)d_ws;
    __half* h16     = (__half*)ws;                     ws += (size_t)ND * 4;
    int*   cnt      = (int*)ws;                        ws += (size_t)N * 4;
    int*   offsets  = (int*)ws;                        ws += (size_t)(N + 2) * 4;
    int*   cursor   = (int*)ws;                        ws += (size_t)N * 4;
    int*   blockSums= (int*)ws;                        ws += 1024 * 4;
    ws = (char*)(((uintptr_t)ws + 7) & ~(uintptr_t)7);
    int2*  srcw     = (int2*)ws;

    const int nb = (N + SCAN_CHUNK - 1) / SCAN_CHUNK;

    hipMemsetAsync(cnt, 0, (size_t)N * sizeof(int), stream);

    // K1: h = old_g @ W (LDS-tiled, fp16 output)
    {
        int grid = (N + GR - 1) / GR;
        gemm64_tile_kernel<<<grid, 256, 0, stream>>>(old_g, W, h16, N);
    }

    // CSR build (XCD-partitioned hist + fill)
    hist_kernel<<<2048, 256, 0, stream>>>(dst, cnt, E, npp);
    block_sum_kernel<<<nb, SCAN_BLK, 0, stream>>>(cnt, N, blockSums);
    top_scan_kernel<<<1, 64, 0, stream>>>(blockSums, nb);
    scan_fill_kernel<<<nb, SCAN_BLK, 0, stream>>>(cnt, N, blockSums, offsets,
                                                  cursor, E);
    fill_kernel<<<2048, 256, 0, stream>>>(src, dst, ew, cursor, srcw, E, npp);

    // K2: per-node accumulation + fused history
    {
        const int block = 256, wpb = block / 64;
        int grid = (N + wpb - 1) / wpb;
        if (grid > 8192) grid = 8192;
        node_kernel<<<grid, block, 0, stream>>>(h16, old_g, hist, offsets, srcw,
                                                out_nodes, out_hist, N);
    }
}

// Round 10
// 215.882 us; speedup vs baseline: 1.9416x; 1.0324x over previous
//
#include <hip/hip_runtime.h>
#include <hip/hip_bf16.h>
#include <hip/hip_fp16.h>

// N = 100000 nodes, D = 64 features, E = 1250000 edges.
// Inputs: old_g[N,D] f32, W[D,D] f32, edge_weight[E,1] f32,
//         history_db[N,D] f32, src[E] i32, dst[E] i32
// Output: concat(nodes_new[N,D], history_new[N,D]) f32.
//
// Pipeline: (1) LDS-tiled fp32 GEMM h = old_g @ W, h stored as fp16;
//           (2) CSR-by-dst build, XCD-partitioned (write combining in L2);
//           (3) node kernel: wave = 4 edge-slots x 16 feature-groups,
//               one 512B gather per 4 edges, shfl_xor slot-reduce,
//               fused history output.
// No float atomics anywhere.

#define D_FEAT 64
#define SCAN_BLK 256
#define SCAN_CHUNK 1024   // 4 elements per thread
#define NPART 8           // = #XCDs; blockIdx%8 ~ XCD (round-robin dispatch)

// ---------------------------------------------------------------------------
// K1: h = old_g @ W.  Block = 256 threads -> 128-row x 64-col tile.
// Epilogue converts to fp16 and stores 8 halves (16 B) per thread-row.
// ---------------------------------------------------------------------------
#define GR 128
#define GPAD 66

__global__ __launch_bounds__(256) void gemm64_tile_kernel(
    const float* __restrict__ g, const float* __restrict__ W,
    __half* __restrict__ h16, int N) {
    __shared__ float Wl[D_FEAT * D_FEAT];
    __shared__ float Gl[GR][GPAD];

    const int tid = threadIdx.x;

    {
        const float4* w4 = reinterpret_cast<const float4*>(W);
        float4* wl4 = reinterpret_cast<float4*>(Wl);
        for (int i = tid; i < D_FEAT * D_FEAT / 4; i += 256) wl4[i] = w4[i];
    }

    const int row0  = blockIdx.x * GR;
    const int nrows = min(GR, N - row0);

    for (int i = tid; i < GR * 16; i += 256) {
        const int r  = i >> 4;
        const int c4 = i & 15;
        if (r < nrows) {
            float4 v = reinterpret_cast<const float4*>(
                           g + (size_t)(row0 + r) * D_FEAT)[c4];
            float* dp = &Gl[r][c4 * 4];
            reinterpret_cast<float2*>(dp)[0] = make_float2(v.x, v.y);
            reinterpret_cast<float2*>(dp)[1] = make_float2(v.z, v.w);
        }
    }
    __syncthreads();

    const int cg = tid & 7;
    const int rg = tid >> 3;
    const int c0 = cg * 8;
    const int r0 = rg * 4;

    float acc[4][8];
#pragma unroll
    for (int i = 0; i < 4; ++i)
#pragma unroll
        for (int j = 0; j < 8; ++j) acc[i][j] = 0.0f;

#pragma unroll 4
    for (int k = 0; k < D_FEAT; ++k) {
        const float4 wa = *reinterpret_cast<const float4*>(&Wl[k * D_FEAT + c0]);
        const float4 wb = *reinterpret_cast<const float4*>(&Wl[k * D_FEAT + c0 + 4]);
        float gv[4];
#pragma unroll
        for (int i = 0; i < 4; ++i) gv[i] = Gl[r0 + i][k];
#pragma unroll
        for (int i = 0; i < 4; ++i) {
            acc[i][0] = fmaf(gv[i], wa.x, acc[i][0]);
            acc[i][1] = fmaf(gv[i], wa.y, acc[i][1]);
            acc[i][2] = fmaf(gv[i], wa.z, acc[i][2]);
            acc[i][3] = fmaf(gv[i], wa.w, acc[i][3]);
            acc[i][4] = fmaf(gv[i], wb.x, acc[i][4]);
            acc[i][5] = fmaf(gv[i], wb.y, acc[i][5]);
            acc[i][6] = fmaf(gv[i], wb.z, acc[i][6]);
            acc[i][7] = fmaf(gv[i], wb.w, acc[i][7]);
        }
    }

#pragma unroll
    for (int i = 0; i < 4; ++i) {
        const int r = r0 + i;
        if (r < nrows) {
            __half2 hb[4];
#pragma unroll
            for (int j = 0; j < 4; ++j)
                hb[j] = __floats2half2_rn(acc[i][2 * j], acc[i][2 * j + 1]);
            *reinterpret_cast<uint4*>(h16 + (size_t)(row0 + r) * D_FEAT + c0) =
                *reinterpret_cast<uint4*>(hb);
        }
    }
}

// ---------------------------------------------------------------------------
// CSR build — XCD-partitioned by dst range.
// ---------------------------------------------------------------------------
__global__ void hist_kernel(const int* __restrict__ dst, int* __restrict__ cnt,
                            int E, int npp) {
    const int part = blockIdx.x & (NPART - 1);
    const int lo = part * npp;
    const int hi = lo + npp;
    const int bid = blockIdx.x >> 3;
    const int nb  = gridDim.x >> 3;
    const int E4 = E >> 2;
    const int4* dst4 = reinterpret_cast<const int4*>(dst);

    int i = bid * blockDim.x + threadIdx.x;
    const int stride = nb * blockDim.x;
    for (; i < E4; i += stride) {
        int4 d = dst4[i];
        if (d.x >= lo && d.x < hi) atomicAdd(&cnt[d.x], 1);
        if (d.y >= lo && d.y < hi) atomicAdd(&cnt[d.y], 1);
        if (d.z >= lo && d.z < hi) atomicAdd(&cnt[d.z], 1);
        if (d.w >= lo && d.w < hi) atomicAdd(&cnt[d.w], 1);
    }
    for (int e = E4 * 4 + bid * blockDim.x + threadIdx.x; e < E;
         e += nb * blockDim.x) {
        int d = dst[e];
        if (d >= lo && d < hi) atomicAdd(&cnt[d], 1);
    }
}

__global__ void block_sum_kernel(const int* __restrict__ cnt, int n,
                                 int* __restrict__ blockSums) {
    __shared__ int lds[SCAN_BLK];
    const int base = blockIdx.x * SCAN_CHUNK;
    const int t = threadIdx.x;
    int s = 0;
#pragma unroll
    for (int i = 0; i < 4; ++i) {
        int idx = base + t * 4 + i;
        s += (idx < n) ? cnt[idx] : 0;
    }
    lds[t] = s;
    __syncthreads();
    for (int off = SCAN_BLK / 2; off > 0; off >>= 1) {
        if (t < off) lds[t] += lds[t + off];
        __syncthreads();
    }
    if (t == 0) blockSums[blockIdx.x] = lds[0];
}

__global__ void top_scan_kernel(int* __restrict__ blockSums, int nb) {
    if (threadIdx.x == 0 && blockIdx.x == 0) {
        int acc = 0;
        for (int i = 0; i < nb; ++i) {
            int v = blockSums[i];
            blockSums[i] = acc;
            acc += v;
        }
    }
}

__global__ void scan_fill_kernel(const int* __restrict__ cnt, int n,
                                 const int* __restrict__ blockSums,
                                 int* __restrict__ offsets,
                                 int* __restrict__ cursor, int E) {
    __shared__ int lds[SCAN_BLK];
    const int base = blockIdx.x * SCAN_CHUNK;
    const int t = threadIdx.x;
    int v[4];
    int s = 0;
#pragma unroll
    for (int i = 0; i < 4; ++i) {
        int idx = base + t * 4 + i;
        v[i] = (idx < n) ? cnt[idx] : 0;
        s += v[i];
    }
    lds[t] = s;
    __syncthreads();
    for (int off = 1; off < SCAN_BLK; off <<= 1) {
        int x = (t >= off) ? lds[t - off] : 0;
        __syncthreads();
        lds[t] += x;
        __syncthreads();
    }
    int run = lds[t] - s + blockSums[blockIdx.x];  // exclusive prefix
#pragma unroll
    for (int i = 0; i < 4; ++i) {
        int idx = base + t * 4 + i;
        if (idx < n) {
            offsets[idx] = run;
            cursor[idx]  = run;
            run += v[i];
        }
    }
    if (blockIdx.x == 0 && t == 0) offsets[n] = E;
}

__global__ void fill_kernel(const int* __restrict__ src,
                            const int* __restrict__ dst,
                            const float* __restrict__ ew,
                            int* __restrict__ cursor,
                            int2* __restrict__ srcw, int E, int npp) {
    const int part = blockIdx.x & (NPART - 1);
    const int lo = part * npp;
    const int hi = lo + npp;
    const int bid = blockIdx.x >> 3;
    const int nb  = gridDim.x >> 3;
    const int E4 = E >> 2;
    const int4* dst4 = reinterpret_cast<const int4*>(dst);

    int i = bid * blockDim.x + threadIdx.x;
    const int stride = nb * blockDim.x;
    for (; i < E4; i += stride) {
        int4 d = dst4[i];
        const int e = i * 4;
        if (d.x >= lo && d.x < hi) {
            int pos = atomicAdd(&cursor[d.x], 1);
            srcw[pos] = make_int2(src[e + 0], __float_as_int(ew[e + 0]));
        }
        if (d.y >= lo && d.y < hi) {
            int pos = atomicAdd(&cursor[d.y], 1);
            srcw[pos] = make_int2(src[e + 1], __float_as_int(ew[e + 1]));
        }
        if (d.z >= lo && d.z < hi) {
            int pos = atomicAdd(&cursor[d.z], 1);
            srcw[pos] = make_int2(src[e + 2], __float_as_int(ew[e + 2]));
        }
        if (d.w >= lo && d.w < hi) {
            int pos = atomicAdd(&cursor[d.w], 1);
            srcw[pos] = make_int2(src[e + 3], __float_as_int(ew[e + 3]));
        }
    }
    for (int e = E4 * 4 + bid * blockDim.x + threadIdx.x; e < E;
         e += nb * blockDim.x) {
        int d = dst[e];
        if (d >= lo && d < hi) {
            int pos = atomicAdd(&cursor[d], 1);
            srcw[pos] = make_int2(src[e], __float_as_int(ew[e]));
        }
    }
}

// ---------------------------------------------------------------------------
// K2: wave = 4 edge-slots x 16 feature-groups. One uint2 (4 fp16) gather per
// lane covers 4 edges' rows per instruction. shfl_xor(16,32) slot-reduce;
// lanes 0-15 write float4. tanh via exp2 + raw v_rcp.
// ---------------------------------------------------------------------------
__device__ __forceinline__ float fast_tanh(float x) {
    float ax = fabsf(x);
    float e  = __builtin_amdgcn_exp2f(-2.885390082f * ax);   // exp(-2|x|)
    float r  = __builtin_amdgcn_rcpf(1.0f + e);
    float t  = fmaf(-2.0f * e, r, 1.0f);                     // (1-e)/(1+e)
    return copysignf(t, x);
}

__global__ void node_kernel(const __half* __restrict__ h16,
                            const float* __restrict__ g,
                            const float* __restrict__ hist,
                            const int* __restrict__ offsets,
                            const int2* __restrict__ srcw,
                            float* __restrict__ out_nodes,
                            float* __restrict__ out_hist, int N) {
    const int lane = threadIdx.x & 63;
    const int wid  = threadIdx.x >> 6;
    const int wpb  = blockDim.x >> 6;
    const int slot = lane >> 4;      // 0..3: which edge of the group of 4
    const int fg   = lane & 15;      // feature group: floats fg*4 .. fg*4+3

    for (int n = blockIdx.x * wpb + wid; n < N; n += gridDim.x * wpb) {
        const int beg = offsets[n];
        const int end = offsets[n + 1];
        const float4 gd = *reinterpret_cast<const float4*>(
            g + (size_t)n * D_FEAT + fg * 4);

        float4 acc = make_float4(0.0f, 0.0f, 0.0f, 0.0f);

        for (int e = beg; e < end; e += 4) {
            const int  ee    = e + slot;
            const bool valid = ee < end;
            const int2 sw = srcw[valid ? ee : beg];
            const float w = __int_as_float(sw.y);
            const uint2 hv = *reinterpret_cast<const uint2*>(
                h16 + (size_t)sw.x * D_FEAT + fg * 4);
            const float2 ha = __half22float2(
                *reinterpret_cast<const __half2*>(&hv.x));
            const float2 hb = __half22float2(
                *reinterpret_cast<const __half2*>(&hv.y));
            const float m = valid ? 1.0f : 0.0f;
            acc.x = fmaf(m, fast_tanh(fmaf(gd.x, w, ha.x)), acc.x);
            acc.y = fmaf(m, fast_tanh(fmaf(gd.y, w, ha.y)), acc.y);
            acc.z = fmaf(m, fast_tanh(fmaf(gd.z, w, hb.x)), acc.z);
            acc.w = fmaf(m, fast_tanh(fmaf(gd.w, w, hb.y)), acc.w);
        }

        // combine the 4 slots (lanes differing in bits 4 and 5)
        acc.x += __shfl_xor(acc.x, 16, 64);
        acc.y += __shfl_xor(acc.y, 16, 64);
        acc.z += __shfl_xor(acc.z, 16, 64);
        acc.w += __shfl_xor(acc.w, 16, 64);
        acc.x += __shfl_xor(acc.x, 32, 64);
        acc.y += __shfl_xor(acc.y, 32, 64);
        acc.z += __shfl_xor(acc.z, 32, 64);
        acc.w += __shfl_xor(acc.w, 32, 64);

        if (lane < 16) {
            const float4 hv4 = *reinterpret_cast<const float4*>(
                hist + (size_t)n * D_FEAT + fg * 4);
            reinterpret_cast<float4*>(out_nodes + (size_t)n * D_FEAT)[fg] = acc;
            float4 o;
            o.x = acc.x + hv4.x;
            o.y = acc.y + hv4.y;
            o.z = acc.z + hv4.z;
            o.w = acc.w + hv4.w;
            reinterpret_cast<float4*>(out_hist + (size_t)n * D_FEAT)[fg] = o;
        }
    }
}

extern "C" void kernel_launch(void* const* d_in, const int* in_sizes, int n_in,
                              void* d_out, int out_size, void* d_ws, size_t ws_size,
                              hipStream_t stream) {
    const float* old_g = (const float*)d_in[0];
    const float* W     = (const float*)d_in[1];
    const float* ew    = (const float*)d_in[2];
    const float* hist  = (const float*)d_in[3];
    const int*   src   = (const int*)d_in[4];
    const int*   dst   = (const int*)d_in[5];

    const int N  = in_sizes[0] / D_FEAT;
    const int E  = in_sizes[4];
    const int ND = N * D_FEAT;
    const int npp = (N + NPART - 1) / NPART;

    float* out_nodes = (float*)d_out;
    float* out_hist  = (float*)d_out + ND;

    // Workspace layout (h region kept at ND*4 bytes for layout stability;
    // only ND*2 used now that h is fp16)
    char* ws = (char*)d_ws;
    __half* h16     = (__half*)ws;                     ws += (size_t)ND * 4;
    int*   cnt      = (int*)ws;                        ws += (size_t)N * 4;
    int*   offsets  = (int*)ws;                        ws += (size_t)(N + 2) * 4;
    int*   cursor   = (int*)ws;                        ws += (size_t)N * 4;
    int*   blockSums= (int*)ws;                        ws += 1024 * 4;
    ws = (char*)(((uintptr_t)ws + 7) & ~(uintptr_t)7);
    int2*  srcw     = (int2*)ws;

    const int nb = (N + SCAN_CHUNK - 1) / SCAN_CHUNK;

    hipMemsetAsync(cnt, 0, (size_t)N * sizeof(int), stream);

    // K1: h = old_g @ W (LDS-tiled, fp16 output)
    {
        int grid = (N + GR - 1) / GR;
        gemm64_tile_kernel<<<grid, 256, 0, stream>>>(old_g, W, h16, N);
    }

    // CSR build (XCD-partitioned hist + fill)
    hist_kernel<<<2048, 256, 0, stream>>>(dst, cnt, E, npp);
    block_sum_kernel<<<nb, SCAN_BLK, 0, stream>>>(cnt, N, blockSums);
    top_scan_kernel<<<1, 64, 0, stream>>>(blockSums, nb);
    scan_fill_kernel<<<nb, SCAN_BLK, 0, stream>>>(cnt, N, blockSums, offsets,
                                                  cursor, E);
    fill_kernel<<<2048, 256, 0, stream>>>(src, dst, ew, cursor, srcw, E, npp);

    // K2: per-node accumulation + fused history
    {
        const int block = 256, wpb = block / 64;
        int grid = (N + wpb - 1) / wpb;
        if (grid > 8192) grid = 8192;
        node_kernel<<<grid, block, 0, stream>>>(h16, old_g, hist, offsets, srcw,
                                                out_nodes, out_hist, N);
    }
}

// Round 11
// 205.319 us; speedup vs baseline: 2.0415x; 1.0514x over previous
//
#include <hip/hip_runtime.h>
#include <hip/hip_bf16.h>
#include <hip/hip_fp16.h>

// N = 100000 nodes, D = 64 features, E = 1250000 edges.
// Inputs: old_g[N,D] f32, W[D,D] f32, edge_weight[E,1] f32,
//         history_db[N,D] f32, src[E] i32, dst[E] i32
// Output: concat(nodes_new[N,D], history_new[N,D]) f32.
//
// Pipeline: (1) LDS-tiled fp32 GEMM h = old_g @ W, h stored as fp16;
//           (2) CSR-by-dst build, XCD-partitioned (write combining in L2);
//           (3) node kernel: wave = 4 edge-slots x 16 feature-groups;
//               one coalesced 512B srcw load per 64 edges + shfl broadcast
//               (no dependent-load chain), 2 gathers in flight,
//               shfl_xor slot-reduce, fused history output.
// No float atomics anywhere.

#define D_FEAT 64
#define SCAN_BLK 256
#define SCAN_CHUNK 1024   // 4 elements per thread
#define NPART 8           // = #XCDs; blockIdx%8 ~ XCD (round-robin dispatch)

// ---------------------------------------------------------------------------
// K1: h = old_g @ W.  Block = 256 threads -> 128-row x 64-col tile.
// ---------------------------------------------------------------------------
#define GR 128
#define GPAD 66

__global__ __launch_bounds__(256) void gemm64_tile_kernel(
    const float* __restrict__ g, const float* __restrict__ W,
    __half* __restrict__ h16, int N) {
    __shared__ float Wl[D_FEAT * D_FEAT];
    __shared__ float Gl[GR][GPAD];

    const int tid = threadIdx.x;

    {
        const float4* w4 = reinterpret_cast<const float4*>(W);
        float4* wl4 = reinterpret_cast<float4*>(Wl);
        for (int i = tid; i < D_FEAT * D_FEAT / 4; i += 256) wl4[i] = w4[i];
    }

    const int row0  = blockIdx.x * GR;
    const int nrows = min(GR, N - row0);

    for (int i = tid; i < GR * 16; i += 256) {
        const int r  = i >> 4;
        const int c4 = i & 15;
        if (r < nrows) {
            float4 v = reinterpret_cast<const float4*>(
                           g + (size_t)(row0 + r) * D_FEAT)[c4];
            float* dp = &Gl[r][c4 * 4];
            reinterpret_cast<float2*>(dp)[0] = make_float2(v.x, v.y);
            reinterpret_cast<float2*>(dp)[1] = make_float2(v.z, v.w);
        }
    }
    __syncthreads();

    const int cg = tid & 7;
    const int rg = tid >> 3;
    const int c0 = cg * 8;
    const int r0 = rg * 4;

    float acc[4][8];
#pragma unroll
    for (int i = 0; i < 4; ++i)
#pragma unroll
        for (int j = 0; j < 8; ++j) acc[i][j] = 0.0f;

#pragma unroll 4
    for (int k = 0; k < D_FEAT; ++k) {
        const float4 wa = *reinterpret_cast<const float4*>(&Wl[k * D_FEAT + c0]);
        const float4 wb = *reinterpret_cast<const float4*>(&Wl[k * D_FEAT + c0 + 4]);
        float gv[4];
#pragma unroll
        for (int i = 0; i < 4; ++i) gv[i] = Gl[r0 + i][k];
#pragma unroll
        for (int i = 0; i < 4; ++i) {
            acc[i][0] = fmaf(gv[i], wa.x, acc[i][0]);
            acc[i][1] = fmaf(gv[i], wa.y, acc[i][1]);
            acc[i][2] = fmaf(gv[i], wa.z, acc[i][2]);
            acc[i][3] = fmaf(gv[i], wa.w, acc[i][3]);
            acc[i][4] = fmaf(gv[i], wb.x, acc[i][4]);
            acc[i][5] = fmaf(gv[i], wb.y, acc[i][5]);
            acc[i][6] = fmaf(gv[i], wb.z, acc[i][6]);
            acc[i][7] = fmaf(gv[i], wb.w, acc[i][7]);
        }
    }

#pragma unroll
    for (int i = 0; i < 4; ++i) {
        const int r = r0 + i;
        if (r < nrows) {
            __half2 hb[4];
#pragma unroll
            for (int j = 0; j < 4; ++j)
                hb[j] = __floats2half2_rn(acc[i][2 * j], acc[i][2 * j + 1]);
            *reinterpret_cast<uint4*>(h16 + (size_t)(row0 + r) * D_FEAT + c0) =
                *reinterpret_cast<uint4*>(hb);
        }
    }
}

// ---------------------------------------------------------------------------
// CSR build — XCD-partitioned by dst range.
// ---------------------------------------------------------------------------
__global__ void hist_kernel(const int* __restrict__ dst, int* __restrict__ cnt,
                            int E, int npp) {
    const int part = blockIdx.x & (NPART - 1);
    const int lo = part * npp;
    const int hi = lo + npp;
    const int bid = blockIdx.x >> 3;
    const int nb  = gridDim.x >> 3;
    const int E4 = E >> 2;
    const int4* dst4 = reinterpret_cast<const int4*>(dst);

    int i = bid * blockDim.x + threadIdx.x;
    const int stride = nb * blockDim.x;
    for (; i < E4; i += stride) {
        int4 d = dst4[i];
        if (d.x >= lo && d.x < hi) atomicAdd(&cnt[d.x], 1);
        if (d.y >= lo && d.y < hi) atomicAdd(&cnt[d.y], 1);
        if (d.z >= lo && d.z < hi) atomicAdd(&cnt[d.z], 1);
        if (d.w >= lo && d.w < hi) atomicAdd(&cnt[d.w], 1);
    }
    for (int e = E4 * 4 + bid * blockDim.x + threadIdx.x; e < E;
         e += nb * blockDim.x) {
        int d = dst[e];
        if (d >= lo && d < hi) atomicAdd(&cnt[d], 1);
    }
}

__global__ void block_sum_kernel(const int* __restrict__ cnt, int n,
                                 int* __restrict__ blockSums) {
    __shared__ int lds[SCAN_BLK];
    const int base = blockIdx.x * SCAN_CHUNK;
    const int t = threadIdx.x;
    int s = 0;
#pragma unroll
    for (int i = 0; i < 4; ++i) {
        int idx = base + t * 4 + i;
        s += (idx < n) ? cnt[idx] : 0;
    }
    lds[t] = s;
    __syncthreads();
    for (int off = SCAN_BLK / 2; off > 0; off >>= 1) {
        if (t < off) lds[t] += lds[t + off];
        __syncthreads();
    }
    if (t == 0) blockSums[blockIdx.x] = lds[0];
}

__global__ void top_scan_kernel(int* __restrict__ blockSums, int nb) {
    if (threadIdx.x == 0 && blockIdx.x == 0) {
        int acc = 0;
        for (int i = 0; i < nb; ++i) {
            int v = blockSums[i];
            blockSums[i] = acc;
            acc += v;
        }
    }
}

__global__ void scan_fill_kernel(const int* __restrict__ cnt, int n,
                                 const int* __restrict__ blockSums,
                                 int* __restrict__ offsets,
                                 int* __restrict__ cursor, int E) {
    __shared__ int lds[SCAN_BLK];
    const int base = blockIdx.x * SCAN_CHUNK;
    const int t = threadIdx.x;
    int v[4];
    int s = 0;
#pragma unroll
    for (int i = 0; i < 4; ++i) {
        int idx = base + t * 4 + i;
        v[i] = (idx < n) ? cnt[idx] : 0;
        s += v[i];
    }
    lds[t] = s;
    __syncthreads();
    for (int off = 1; off < SCAN_BLK; off <<= 1) {
        int x = (t >= off) ? lds[t - off] : 0;
        __syncthreads();
        lds[t] += x;
        __syncthreads();
    }
    int run = lds[t] - s + blockSums[blockIdx.x];  // exclusive prefix
#pragma unroll
    for (int i = 0; i < 4; ++i) {
        int idx = base + t * 4 + i;
        if (idx < n) {
            offsets[idx] = run;
            cursor[idx]  = run;
            run += v[i];
        }
    }
    if (blockIdx.x == 0 && t == 0) offsets[n] = E;
}

__global__ void fill_kernel(const int* __restrict__ src,
                            const int* __restrict__ dst,
                            const float* __restrict__ ew,
                            int* __restrict__ cursor,
                            int2* __restrict__ srcw, int E, int npp) {
    const int part = blockIdx.x & (NPART - 1);
    const int lo = part * npp;
    const int hi = lo + npp;
    const int bid = blockIdx.x >> 3;
    const int nb  = gridDim.x >> 3;
    const int E4 = E >> 2;
    const int4* dst4 = reinterpret_cast<const int4*>(dst);

    int i = bid * blockDim.x + threadIdx.x;
    const int stride = nb * blockDim.x;
    for (; i < E4; i += stride) {
        int4 d = dst4[i];
        const int e = i * 4;
        if (d.x >= lo && d.x < hi) {
            int pos = atomicAdd(&cursor[d.x], 1);
            srcw[pos] = make_int2(src[e + 0], __float_as_int(ew[e + 0]));
        }
        if (d.y >= lo && d.y < hi) {
            int pos = atomicAdd(&cursor[d.y], 1);
            srcw[pos] = make_int2(src[e + 1], __float_as_int(ew[e + 1]));
        }
        if (d.z >= lo && d.z < hi) {
            int pos = atomicAdd(&cursor[d.z], 1);
            srcw[pos] = make_int2(src[e + 2], __float_as_int(ew[e + 2]));
        }
        if (d.w >= lo && d.w < hi) {
            int pos = atomicAdd(&cursor[d.w], 1);
            srcw[pos] = make_int2(src[e + 3], __float_as_int(ew[e + 3]));
        }
    }
    for (int e = E4 * 4 + bid * blockDim.x + threadIdx.x; e < E;
         e += nb * blockDim.x) {
        int d = dst[e];
        if (d >= lo && d < hi) {
            int pos = atomicAdd(&cursor[d], 1);
            srcw[pos] = make_int2(src[e], __float_as_int(ew[e]));
        }
    }
}

// ---------------------------------------------------------------------------
// K2: wave = 4 edge-slots x 16 feature-groups. srcw fetched 64-at-a-time
// coalesced, broadcast via shfl (no dependent load); 2 gathers in flight.
// ---------------------------------------------------------------------------
__device__ __forceinline__ float fast_tanh(float x) {
    float ax = fabsf(x);
    float e  = __builtin_amdgcn_exp2f(-2.885390082f * ax);   // exp(-2|x|)
    float r  = __builtin_amdgcn_rcpf(1.0f + e);
    float t  = fmaf(-2.0f * e, r, 1.0f);                     // (1-e)/(1+e)
    return copysignf(t, x);
}

__global__ void node_kernel(const __half* __restrict__ h16,
                            const float* __restrict__ g,
                            const float* __restrict__ hist,
                            const int* __restrict__ offsets,
                            const int2* __restrict__ srcw,
                            float* __restrict__ out_nodes,
                            float* __restrict__ out_hist, int N) {
    const int lane = threadIdx.x & 63;
    const int wid  = threadIdx.x >> 6;
    const int wpb  = blockDim.x >> 6;
    const int slot = lane >> 4;      // 0..3: edge within group of 4
    const int fg   = lane & 15;      // feature group: floats fg*4 .. fg*4+3

    for (int n = blockIdx.x * wpb + wid; n < N; n += gridDim.x * wpb) {
        const int beg = offsets[n];
        const int end = offsets[n + 1];
        const float4 gd = *reinterpret_cast<const float4*>(
            g + (size_t)n * D_FEAT + fg * 4);

        float4 acc = make_float4(0.0f, 0.0f, 0.0f, 0.0f);

        for (int base = beg; base < end; base += 64) {
            const int chunk = min(64, end - base);
            // one coalesced load: lane l holds srcw[base+l] (clamped)
            const int2 my_sw = srcw[base + min(lane, chunk - 1)];

            for (int g0 = 0; g0 < chunk; g0 += 8) {
                // group A: edges g0+slot, group B: edges g0+4+slot
                const int  ia = g0 + slot;
                const int  ib = ia + 4;
                const int  sa = __shfl(my_sw.x, ia, 64);
                const float wa = __int_as_float(__shfl(my_sw.y, ia, 64));
                const int  sb = __shfl(my_sw.x, ib, 64);
                const float wb = __int_as_float(__shfl(my_sw.y, ib, 64));
                const bool va = ia < chunk;
                const bool vb = ib < chunk;
                // both gathers issued before either consumed
                const uint2 hva = *reinterpret_cast<const uint2*>(
                    h16 + (size_t)sa * D_FEAT + fg * 4);
                const uint2 hvb = *reinterpret_cast<const uint2*>(
                    h16 + (size_t)sb * D_FEAT + fg * 4);

                const float2 a0 = __half22float2(
                    *reinterpret_cast<const __half2*>(&hva.x));
                const float2 a1 = __half22float2(
                    *reinterpret_cast<const __half2*>(&hva.y));
                const float ma = va ? 1.0f : 0.0f;
                acc.x = fmaf(ma, fast_tanh(fmaf(gd.x, wa, a0.x)), acc.x);
                acc.y = fmaf(ma, fast_tanh(fmaf(gd.y, wa, a0.y)), acc.y);
                acc.z = fmaf(ma, fast_tanh(fmaf(gd.z, wa, a1.x)), acc.z);
                acc.w = fmaf(ma, fast_tanh(fmaf(gd.w, wa, a1.y)), acc.w);

                const float2 b0 = __half22float2(
                    *reinterpret_cast<const __half2*>(&hvb.x));
                const float2 b1 = __half22float2(
                    *reinterpret_cast<const __half2*>(&hvb.y));
                const float mb = vb ? 1.0f : 0.0f;
                acc.x = fmaf(mb, fast_tanh(fmaf(gd.x, wb, b0.x)), acc.x);
                acc.y = fmaf(mb, fast_tanh(fmaf(gd.y, wb, b0.y)), acc.y);
                acc.z = fmaf(mb, fast_tanh(fmaf(gd.z, wb, b1.x)), acc.z);
                acc.w = fmaf(mb, fast_tanh(fmaf(gd.w, wb, b1.y)), acc.w);
            }
        }

        // combine the 4 slots (lanes differing in bits 4 and 5)
        acc.x += __shfl_xor(acc.x, 16, 64);
        acc.y += __shfl_xor(acc.y, 16, 64);
        acc.z += __shfl_xor(acc.z, 16, 64);
        acc.w += __shfl_xor(acc.w, 16, 64);
        acc.x += __shfl_xor(acc.x, 32, 64);
        acc.y += __shfl_xor(acc.y, 32, 64);
        acc.z += __shfl_xor(acc.z, 32, 64);
        acc.w += __shfl_xor(acc.w, 32, 64);

        if (lane < 16) {
            const float4 hv4 = *reinterpret_cast<const float4*>(
                hist + (size_t)n * D_FEAT + fg * 4);
            reinterpret_cast<float4*>(out_nodes + (size_t)n * D_FEAT)[fg] = acc;
            float4 o;
            o.x = acc.x + hv4.x;
            o.y = acc.y + hv4.y;
            o.z = acc.z + hv4.z;
            o.w = acc.w + hv4.w;
            reinterpret_cast<float4*>(out_hist + (size_t)n * D_FEAT)[fg] = o;
        }
    }
}

extern "C" void kernel_launch(void* const* d_in, const int* in_sizes, int n_in,
                              void* d_out, int out_size, void* d_ws, size_t ws_size,
                              hipStream_t stream) {
    const float* old_g = (const float*)d_in[0];
    const float* W     = (const float*)d_in[1];
    const float* ew    = (const float*)d_in[2];
    const float* hist  = (const float*)d_in[3];
    const int*   src   = (const int*)d_in[4];
    const int*   dst   = (const int*)d_in[5];

    const int N  = in_sizes[0] / D_FEAT;
    const int E  = in_sizes[4];
    const int ND = N * D_FEAT;
    const int npp = (N + NPART - 1) / NPART;

    float* out_nodes = (float*)d_out;
    float* out_hist  = (float*)d_out + ND;

    // Workspace layout (h region kept at ND*4 bytes for layout stability;
    // only ND*2 used now that h is fp16)
    char* ws = (char*)d_ws;
    __half* h16     = (__half*)ws;                     ws += (size_t)ND * 4;
    int*   cnt      = (int*)ws;                        ws += (size_t)N * 4;
    int*   offsets  = (int*)ws;                        ws += (size_t)(N + 2) * 4;
    int*   cursor   = (int*)ws;                        ws += (size_t)N * 4;
    int*   blockSums= (int*)ws;                        ws += 1024 * 4;
    ws = (char*)(((uintptr_t)ws + 7) & ~(uintptr_t)7);
    int2*  srcw     = (int2*)ws;

    const int nb = (N + SCAN_CHUNK - 1) / SCAN_CHUNK;

    hipMemsetAsync(cnt, 0, (size_t)N * sizeof(int), stream);

    // K1: h = old_g @ W (LDS-tiled, fp16 output)
    {
        int grid = (N + GR - 1) / GR;
        gemm64_tile_kernel<<<grid, 256, 0, stream>>>(old_g, W, h16, N);
    }

    // CSR build (XCD-partitioned hist + fill)
    hist_kernel<<<2048, 256, 0, stream>>>(dst, cnt, E, npp);
    block_sum_kernel<<<nb, SCAN_BLK, 0, stream>>>(cnt, N, blockSums);
    top_scan_kernel<<<1, 64, 0, stream>>>(blockSums, nb);
    scan_fill_kernel<<<nb, SCAN_BLK, 0, stream>>>(cnt, N, blockSums, offsets,
                                                  cursor, E);
    fill_kernel<<<2048, 256, 0, stream>>>(src, dst, ew, cursor, srcw, E, npp);

    // K2: per-node accumulation + fused history
    {
        const int block = 256, wpb = block / 64;
        int grid = (N + wpb - 1) / wpb;
        if (grid > 8192) grid = 8192;
        node_kernel<<<grid, block, 0, stream>>>(h16, old_g, hist, offsets, srcw,
                                                out_nodes, out_hist, N);
    }
}